// Round 1
// baseline (168.806 us; speedup 1.0000x reference)
//
#include <hip/hip_runtime.h>

#define BB 512
#define SS 512
#define TT 64
#define TSTRIDE 66   // transitions is (66,66)

__device__ __forceinline__ float lane_bcast(float v, int l) {
    return __int_as_float(__builtin_amdgcn_readlane(__float_as_int(v), l));
}
__device__ __forceinline__ float first_lane(float v) {
    return __int_as_float(__builtin_amdgcn_readfirstlane(__float_as_int(v)));
}

// One wave per batch. Lane j owns score[j] and E-column j.
__global__ __launch_bounds__(64) void crf_scan_kernel(
    const float* __restrict__ emissions,   // [B,S,T]
    const float* __restrict__ mask,        // [B,S]
    const float* __restrict__ trans,       // [66,66]
    float* __restrict__ logZ_out)          // [B]
{
    const int b = blockIdx.x;
    const int j = threadIdx.x;   // 0..63

    // E[i][j] = exp(tt[i][j]); lane j holds column j in registers.
    float Ecol[TT];
    #pragma unroll
    for (int i = 0; i < TT; ++i)
        Ecol[i] = __expf(trans[i * TSTRIDE + j]);

    const float* em = emissions + (size_t)b * SS * TT;
    const float* mk = mask + (size_t)b * SS;

    // score0[j] = (em[0,j] + trans[j, start=64]) * mask[b,0]
    float score = (em[j] + trans[j * TSTRIDE + TT]) * mk[0];

    // rolling emission prefetch, depth 3
    float e1 = em[1 * TT + j];
    float e2 = em[2 * TT + j];
    float e3 = em[3 * TT + j];
    float mv1 = mk[1];

    for (int s = 1; s < SS; ++s) {
        float emit = e1;
        float mval = mv1;
        e1 = e2; e2 = e3;
        if (s + 3 < SS) e3 = em[(s + 3) * TT + j];
        if (s + 1 < SS) mv1 = mk[s + 1];

        // cheap normalizer: any lane's score is within ~6 of the max
        float m0 = first_lane(score);
        float p  = __expf(score - m0);

        float a0 = 0.f, a1 = 0.f, a2 = 0.f, a3 = 0.f;
        #pragma unroll
        for (int i = 0; i < TT; i += 4) {
            a0 = __builtin_fmaf(lane_bcast(p, i + 0), Ecol[i + 0], a0);
            a1 = __builtin_fmaf(lane_bcast(p, i + 1), Ecol[i + 1], a1);
            a2 = __builtin_fmaf(lane_bcast(p, i + 2), Ecol[i + 2], a2);
            a3 = __builtin_fmaf(lane_bcast(p, i + 3), Ecol[i + 3], a3);
        }
        score = m0 + __logf((a0 + a1) + (a2 + a3)) + emit * mval;
    }

    // + trans[stop=65, j], then wave logsumexp
    score += trans[65 * TSTRIDE + j];

    float m = score;
    #pragma unroll
    for (int off = 32; off; off >>= 1) m = fmaxf(m, __shfl_xor(m, off));
    float e = __expf(score - m);
    #pragma unroll
    for (int off = 32; off; off >>= 1) e += __shfl_xor(e, off);
    if (j == 0) logZ_out[b] = m + __logf(e);
}

// One wave per batch: gold path score.
__global__ __launch_bounds__(64) void crf_gold_kernel(
    const float* __restrict__ emissions,
    const int* __restrict__ tags,          // [B,S] int32
    const float* __restrict__ mask,
    const float* __restrict__ trans,
    float* __restrict__ gold_out)          // [B]
{
    const int b = blockIdx.x;
    const int l = threadIdx.x;
    const int*   tg = tags + (size_t)b * SS;
    const float* mk = mask + (size_t)b * SS;
    const float* em = emissions + (size_t)b * SS * TT;

    float acc  = 0.f;
    float msum = 0.f;
    for (int s = l; s < SS; s += 64) {
        float m = mk[s];
        msum += m;
        if (s > 0) {
            int curr = tg[s], prev = tg[s - 1];
            acc += (trans[curr * TSTRIDE + prev] + em[s * TT + curr]) * m;
        } else {
            int t0 = tg[0];
            acc += (em[t0] + trans[t0 * TSTRIDE + TT]) * m;
        }
    }
    #pragma unroll
    for (int off = 32; off; off >>= 1) {
        acc  += __shfl_xor(acc,  off);
        msum += __shfl_xor(msum, off);
    }
    if (l == 0) {
        int len  = (int)(msum + 0.5f);
        int last = tg[len - 1];
        acc += trans[65 * TSTRIDE + last];
        gold_out[b] = acc;
    }
}

__global__ __launch_bounds__(256) void crf_final_kernel(
    const float* __restrict__ logZ,
    const float* __restrict__ gold,
    float* __restrict__ out)
{
    __shared__ float sdata[4];
    int t = threadIdx.x;
    float v = 0.f;
    for (int b = t; b < BB; b += 256) v += logZ[b] - gold[b];
    #pragma unroll
    for (int off = 32; off; off >>= 1) v += __shfl_xor(v, off);
    if ((t & 63) == 0) sdata[t >> 6] = v;
    __syncthreads();
    if (t == 0) out[0] = (sdata[0] + sdata[1] + sdata[2] + sdata[3]) * (1.0f / BB);
}

extern "C" void kernel_launch(void* const* d_in, const int* in_sizes, int n_in,
                              void* d_out, int out_size, void* d_ws, size_t ws_size,
                              hipStream_t stream) {
    const float* emissions = (const float*)d_in[0];
    const int*   tags      = (const int*)d_in[1];
    const float* mask      = (const float*)d_in[2];
    const float* trans     = (const float*)d_in[3];
    float* out  = (float*)d_out;
    float* logZ = (float*)d_ws;
    float* gold = logZ + BB;

    crf_gold_kernel<<<BB, 64, 0, stream>>>(emissions, tags, mask, trans, gold);
    crf_scan_kernel<<<BB, 64, 0, stream>>>(emissions, mask, trans, logZ);
    crf_final_kernel<<<1, 256, 0, stream>>>(logZ, gold, out);
}